// Round 11
// baseline (303.107 us; speedup 1.0000x reference)
//
#include <hip/hip_runtime.h>

using half8   = __attribute__((ext_vector_type(8))) _Float16;
using f32x4   = __attribute__((ext_vector_type(4))) float;
using ushort8 = __attribute__((ext_vector_type(8))) unsigned short;

__device__ __forceinline__ void gload16(const void* g, void* l) {
  __builtin_amdgcn_global_load_lds(
      (const __attribute__((address_space(1))) void*)g,
      (__attribute__((address_space(3))) void*)l, 16, 0, 0);
}

// XCD-aware bijective swizzle with 8x4 2D rects. Requires gx%8==0, gy%4==0.
__device__ __forceinline__ void xcd_swizzle(int& x, int& y, int& z) {
  const int gx = gridDim.x, gy = gridDim.y;
  const int nwg = gx * gy * gridDim.z;
  const int f = blockIdx.x + gx * (blockIdx.y + gy * blockIdx.z);
  const int w = (f & 7) * (nwg >> 3) + (f >> 3);
  const int r = w >> 5, u = w & 31;
  const int nrx = gx >> 3, nry = gy >> 2;
  const int pz  = nrx * nry;
  const int rz  = r / pz, rr = r % pz;
  x = (rr % nrx) * 8 + (u & 7);
  y = (rr / nrx) * 4 + (u >> 3);
  z = rz;
}

// ---------------- cast fp32 -> fp16 ----------------
__global__ __launch_bounds__(256) void cast_f32_f16(
    const float* __restrict__ in, unsigned short* __restrict__ out, long n) {
  long i = ((long)blockIdx.x * 256 + threadIdx.x) * 8;
  if (i >= n) return;
  float4 a = *(const float4*)(in + i);
  float4 b = *(const float4*)(in + i + 4);
  union { _Float16 h[8]; ushort8 u; } r;
  r.h[0] = (_Float16)a.x; r.h[1] = (_Float16)a.y;
  r.h[2] = (_Float16)a.z; r.h[3] = (_Float16)a.w;
  r.h[4] = (_Float16)b.x; r.h[5] = (_Float16)b.y;
  r.h[6] = (_Float16)b.z; r.h[7] = (_Float16)b.w;
  *(ushort8*)(out + i) = r.u;
}

// ======== B-direct NT GEMM: C[M,N] = A[M,K]*B[N,K]^T ========
// BM=BN=128, BK=64, 256 threads (2Mx2N waves), per-wave 64x64 (4x4 of 16x16x32).
// B-fragments loaded DIRECTLY global->VGPR (8 contiguous halves per lane:
// row bn+wc*64+ni*16+fr, k = kt+(ks*4+fq)*8) -- B panels are L2/L3-resident
// (W 6MB, k/vT 4MB/batch; XCD rect-swizzle shares them across co-resident
// blocks). Halves LDS traffic vs staging both operands (96KB/tile -> 48KB),
// balancing LDS (~565cyc) / L2 (~700cyc) / MFMA (~621cyc) pipes. B-regs
// double-buffered: loads for tile t+1 issue during tile t. A stays
// gload_lds-staged, XOR-swizzled, double-buffered. LDS 32KB -> 2 blocks/CU.
// NOTE R10 bug fixed: macro-local tile index named tcur, loop var tt
// (TILE_BODY(t,...) with 'const int t=(T)' self-shadowed -> UB -> OOB reads).
template <int MODE>
__global__ __launch_bounds__(256, 2) void gemm_bd(
    const unsigned short* __restrict__ Ab, const unsigned short* __restrict__ Bb,
    int K, int lda, int ldb, long sA, long sB,
    void* __restrict__ o0, void* __restrict__ o1, void* __restrict__ o2) {
  constexpr int ASZ = 128 * 64;                  // halves per A slot
  __shared__ unsigned short ldsA[2 * ASZ];       // 32 KB

  const int tid  = threadIdx.x;
  const int lane = tid & 63;
  const int wv   = tid >> 6;
  const int wr   = wv >> 1, wc = wv & 1;
  const int fr   = lane & 15, fq = lane >> 4;
  int bxi, byi, bzi;
  xcd_swizzle(bxi, byi, bzi);
  const int bm = byi * 128;
  const int bn = bxi * 128;
  const int bz = bzi;

  const unsigned short* A = Ab + (long)bz * sA;
  const unsigned short* B = Bb + (long)bz * sB;

  // A staging: thread t -> row tid>>3 per 32-row issue, granule tid&7,
  // source pre-swizzled (gload_lds writes linearly; reads apply same XOR)
  const int row_s = tid >> 3;
  const int col_s = ((tid & 7) ^ (row_s & 7)) * 8;
  const unsigned short* aS = A + (long)(bm + row_s) * lda + col_s;

  // A-frag read offsets (bytes), swizzled
  const int kg0 = ((0 * 4 + fq) ^ (fr & 7)) * 16;
  const int kg1 = ((1 * 4 + fq) ^ (fr & 7)) * 16;
  const int aRd = (wr * 64 + fr) * 128;  // + mi*2048 + kg

  // B-direct row bases (4 rows per lane), true k layout (no swizzle)
  const unsigned short* bR0 = B + (long)(bn + wc * 64 + 0  + fr) * ldb + fq * 8;
  const unsigned short* bR1 = B + (long)(bn + wc * 64 + 16 + fr) * ldb + fq * 8;
  const unsigned short* bR2 = B + (long)(bn + wc * 64 + 32 + fr) * ldb + fq * 8;
  const unsigned short* bR3 = B + (long)(bn + wc * 64 + 48 + fr) * ldb + fq * 8;

  f32x4 acc[4][4] = {};
  half8 bfA[4][2], bfB[4][2];      // double-buffered B frags
  half8 a0[2], a1[2], a2[2], a3[2];

  const int nt = K / 64;

#define LOADB(DST, T)                                                              \
  {                                                                                \
    const long ktb = (long)(T) * 64;                                               \
    DST[0][0] = *(const half8*)(bR0 + ktb);      /* ks0: granule fq   */           \
    DST[0][1] = *(const half8*)(bR0 + ktb + 32); /* ks1: granule 4+fq */           \
    DST[1][0] = *(const half8*)(bR1 + ktb);                                        \
    DST[1][1] = *(const half8*)(bR1 + ktb + 32);                                   \
    DST[2][0] = *(const half8*)(bR2 + ktb);                                        \
    DST[2][1] = *(const half8*)(bR2 + ktb + 32);                                   \
    DST[3][0] = *(const half8*)(bR3 + ktb);                                        \
    DST[3][1] = *(const half8*)(bR3 + ktb + 32);                                   \
  }
#define STAGE_A(SL, T)                                                             \
  {                                                                                \
    const long kta = (long)(T) * 64;                                               \
    unsigned short* d = ldsA + (SL) * ASZ + wv * 512;                              \
    _Pragma("unroll") for (int i = 0; i < 4; ++i)                                  \
      gload16(aS + (long)(i * 32) * lda + kta, d + i * 2048);                      \
  }
#define RDA(DST, MI)                                                               \
  DST[0] = *(const half8*)(lA + aRd + (MI) * 2048 + kg0);                          \
  DST[1] = *(const half8*)(lA + aRd + (MI) * 2048 + kg1);
#define MFMAQ(MI, AA, BF)                                                          \
  __builtin_amdgcn_s_setprio(1);                                                   \
  _Pragma("unroll") for (int ks = 0; ks < 2; ++ks)                                 \
  _Pragma("unroll") for (int ni = 0; ni < 4; ++ni)                                 \
    acc[MI][ni] = __builtin_amdgcn_mfma_f32_16x16x32_f16(                          \
        AA[ks], BF[ni][ks], acc[MI][ni], 0, 0, 0);                                 \
  __builtin_amdgcn_s_setprio(0);

#define TILE_BODY(T, BC, BN_)                                                      \
  {                                                                                \
    const int tcur = (T);                                                          \
    const int sl = tcur & 1;                                                       \
    const char* lA = (const char*)(ldsA + sl * ASZ);                               \
    if (tcur + 1 < nt) LOADB(BN_, tcur + 1)  /* B(t+1) -> regs, used next tile */  \
    RDA(a0, 0)                                                                     \
    RDA(a1, 1)                                                                     \
    if (tcur + 1 < nt) STAGE_A(sl ^ 1, tcur + 1)                                   \
    MFMAQ(0, a0, BC)                                                               \
    RDA(a2, 2)                                                                     \
    MFMAQ(1, a1, BC)                                                               \
    RDA(a3, 3)                                                                     \
    MFMAQ(2, a2, BC)                                                               \
    MFMAQ(3, a3, BC)                                                               \
    __syncthreads();                                                               \
  }

  // ---- prologue: stage A(0), load B(0) regs ----
  STAGE_A(0, 0)
  LOADB(bfA, 0)
  __syncthreads();

  for (int tt = 0; tt < nt; tt += 2) {
    TILE_BODY(tt, bfA, bfB)
    TILE_BODY(tt + 1, bfB, bfA)
  }
#undef TILE_BODY
#undef LOADB
#undef STAGE_A
#undef RDA
#undef MFMAQ

  // epilogue: C/D layout col=lane&15, row=fq*4+reg
  const int row0 = bm + wr * 64 + fq * 4;
  const int col0 = bn + wc * 64 + fr;
#pragma unroll
  for (int mi = 0; mi < 4; ++mi) {
#pragma unroll
    for (int ni = 0; ni < 4; ++ni) {
      f32x4 c = acc[mi][ni];
      const long r0 = row0 + mi * 16;
      const long e  = col0 + ni * 16;
      if constexpr (MODE == 0) {
        _Float16* q  = (_Float16*)o0;
        _Float16* kk = (_Float16*)o1;
        _Float16* vv = (_Float16*)o2;
#pragma unroll
        for (int j = 0; j < 4; ++j) {
          const long i = r0 + j;
          const float val = c[j];
          if (e < 1024)      q [i * 1024 + e]          = (_Float16)(val * 0.03125f);
          else if (e < 2048) kk[i * 1024 + (e - 1024)] = (_Float16)val;
          else               vv[i * 1024 + (e - 2048)] = (_Float16)val;
        }
      } else if constexpr (MODE == 1) {
        float* C = (float*)o0 + (long)bz * 2048 * 2048;
#pragma unroll
        for (int j = 0; j < 4; ++j) C[(r0 + j) * 2048 + e] = c[j];
      } else {
        float* C = (float*)o0 + (long)bz * 2048 * 1024;
#pragma unroll
        for (int j = 0; j < 4; ++j) C[(r0 + j) * 1024 + e] = c[j];
      }
    }
  }
}

// ---------------- transpose v [b][n][d] -> vT [b][d][n] (fp16) ----------------
__global__ __launch_bounds__(256) void transpose_v(
    const unsigned short* __restrict__ v, unsigned short* __restrict__ vT) {
  __shared__ unsigned short t[64][72];  // +8 pad
  const long b = blockIdx.z;
  const unsigned short* vb = v + b * (2048L * 1024);
  unsigned short* ob = vT + b * (1024L * 2048);
  const int n0 = blockIdx.y * 64;
  const int d0 = blockIdx.x * 64;
  const int tid = threadIdx.x;
  const int r  = tid >> 2;
  const int c0 = (tid & 3) * 16;
  const unsigned short* src = vb + (long)(n0 + r) * 1024 + d0 + c0;
  *(ushort4*)&t[r][c0]      = *(const ushort4*)(src);
  *(ushort4*)&t[r][c0 + 4]  = *(const ushort4*)(src + 4);
  *(ushort4*)&t[r][c0 + 8]  = *(const ushort4*)(src + 8);
  *(ushort4*)&t[r][c0 + 12] = *(const ushort4*)(src + 12);
  __syncthreads();
  union { unsigned short h[8]; ushort8 u; } w0, w1;
#pragma unroll
  for (int j = 0; j < 8; ++j) w0.h[j] = t[c0 + j][r];
#pragma unroll
  for (int j = 0; j < 8; ++j) w1.h[j] = t[c0 + 8 + j][r];
  unsigned short* dst = ob + (long)(d0 + r) * 2048 + n0 + c0;
  *(ushort8*)dst       = w0.u;
  *(ushort8*)(dst + 8) = w1.u;
}

// ---------------- row softmax fp32[2048] -> fp16 in-place ----------------
__global__ __launch_bounds__(256) void softmax_rows(float* __restrict__ S) {
  const long row = blockIdx.x;
  float* p = S + row * 2048;
  const int t = threadIdx.x;
  float4 v0 = *(const float4*)(p + t * 8);
  float4 v1 = *(const float4*)(p + t * 8 + 4);
  float f[8] = {v0.x, v0.y, v0.z, v0.w, v1.x, v1.y, v1.z, v1.w};
  float m = f[0];
#pragma unroll
  for (int j = 1; j < 8; ++j) m = fmaxf(m, f[j]);
  for (int o = 32; o; o >>= 1) m = fmaxf(m, __shfl_xor(m, o));
  __shared__ float redm[4];
  if (!(t & 63)) redm[t >> 6] = m;
  __syncthreads();
  m = fmaxf(fmaxf(redm[0], redm[1]), fmaxf(redm[2], redm[3]));
  float e[8], s = 0.f;
#pragma unroll
  for (int j = 0; j < 8; ++j) { e[j] = __expf(f[j] - m); s += e[j]; }
  for (int o = 32; o; o >>= 1) s += __shfl_xor(s, o);
  __shared__ float reds[4];
  if (!(t & 63)) reds[t >> 6] = s;
  __syncthreads();
  s = reds[0] + reds[1] + reds[2] + reds[3];
  const float inv = 1.0f / s;
  union { _Float16 h[8]; ushort8 u; } r;
#pragma unroll
  for (int j = 0; j < 8; ++j) r.h[j] = (_Float16)(e[j] * inv);
  *(ushort8*)((unsigned short*)p + t * 8) = r.u;  // P fp16, row pitch 4096 halves
}

extern "C" void kernel_launch(void* const* d_in, const int* in_sizes, int n_in,
                              void* d_out, int out_size, void* d_ws, size_t ws_size,
                              hipStream_t stream) {
  const float* x = (const float*)d_in[0];   // [4,2048,1024]
  const float* W = (const float*)d_in[1];   // [3072,1024]
  float* out = (float*)d_out;               // [4,2048,1024] fp32
  char* ws = (char*)d_ws;

  const long MB16 = 16777216;  // 8192*1024*2 bytes
  unsigned short* q  = (unsigned short*)(ws);
  unsigned short* k  = (unsigned short*)(ws + MB16);
  unsigned short* vT = (unsigned short*)(ws + 2 * MB16);
  float*          S  = (float*)(ws + 3 * MB16);              // 64 MiB
  // aliased into S region (dead before S is written):
  unsigned short* xb = (unsigned short*)(ws + 3 * MB16);
  unsigned short* wb = (unsigned short*)(ws + 4 * MB16);
  unsigned short* v  = (unsigned short*)(ws + 4 * MB16 + 6291456);

  // 1. casts
  cast_f32_f16<<<4096, 256, 0, stream>>>(x, xb, 8388608L);
  cast_f32_f16<<<1536, 256, 0, stream>>>(W, wb, 3145728L);
  // 2. qkv = x @ W^T (M=8192, N=3072, K=1024): 24x64 = 1536 blocks
  gemm_bd<0><<<dim3(24, 64, 1), 256, 0, stream>>>(
      xb, wb, 1024, 1024, 1024, 0L, 0L, q, k, v);
  // 3. v -> vT per batch
  transpose_v<<<dim3(16, 32, 4), 256, 0, stream>>>(v, vT);
  // 4. S = (q*scale) @ k^T per batch (M=N=2048, K=1024): 16x16x4 = 1024 blocks
  gemm_bd<1><<<dim3(16, 16, 4), 256, 0, stream>>>(
      q, k, 1024, 1024, 1024, 2048L * 1024, 2048L * 1024, S, nullptr, nullptr);
  // 5. row softmax, P fp16 in place (row pitch 4096 halves)
  softmax_rows<<<8192, 256, 0, stream>>>(S);
  // 6. out = P @ vT^T per batch (M=2048, N=1024, K=2048): 8x16x4 = 512 blocks
  gemm_bd<2><<<dim3(8, 16, 4), 256, 0, stream>>>(
      (unsigned short*)S, vT, 2048, 4096, 2048, 2048L * 4096, 1024L * 2048,
      out, nullptr, nullptr);
}

// Round 12
// 192.626 us; speedup vs baseline: 1.5735x; 1.5735x over previous
//
#include <hip/hip_runtime.h>

using half8   = __attribute__((ext_vector_type(8))) _Float16;
using f32x4   = __attribute__((ext_vector_type(4))) float;
using ushort8 = __attribute__((ext_vector_type(8))) unsigned short;

__device__ __forceinline__ void gload16(const void* g, void* l) {
  __builtin_amdgcn_global_load_lds(
      (const __attribute__((address_space(1))) void*)g,
      (__attribute__((address_space(3))) void*)l, 16, 0, 0);
}

// XCD-aware bijective swizzle with 8x4 2D rects. Requires gx%8==0, gy%4==0.
__device__ __forceinline__ void xcd_swizzle(int& x, int& y, int& z) {
  const int gx = gridDim.x, gy = gridDim.y;
  const int nwg = gx * gy * gridDim.z;
  const int f = blockIdx.x + gx * (blockIdx.y + gy * blockIdx.z);
  const int w = (f & 7) * (nwg >> 3) + (f >> 3);
  const int r = w >> 5, u = w & 31;
  const int nrx = gx >> 3, nry = gy >> 2;
  const int pz  = nrx * nry;
  const int rz  = r / pz, rr = r % pz;
  x = (rr % nrx) * 8 + (u & 7);
  y = (rr / nrx) * 4 + (u >> 3);
  z = rz;
}

// ---------------- cast fp32 -> fp16 ----------------
__global__ __launch_bounds__(256) void cast_f32_f16(
    const float* __restrict__ in, unsigned short* __restrict__ out, long n) {
  long i = ((long)blockIdx.x * 256 + threadIdx.x) * 8;
  if (i >= n) return;
  float4 a = *(const float4*)(in + i);
  float4 b = *(const float4*)(in + i + 4);
  union { _Float16 h[8]; ushort8 u; } r;
  r.h[0] = (_Float16)a.x; r.h[1] = (_Float16)a.y;
  r.h[2] = (_Float16)a.z; r.h[3] = (_Float16)a.w;
  r.h[4] = (_Float16)b.x; r.h[5] = (_Float16)b.y;
  r.h[6] = (_Float16)b.z; r.h[7] = (_Float16)b.w;
  *(ushort8*)(out + i) = r.u;
}

// ======== FAT-WAVE NT GEMM: C[M,N] = A[M,K]*B[N,K]^T ========
// 4 waves in a 2x2 grid, per-wave tile 128 x (16*N_REP). BM=256, BN=32*N_REP,
// BK=64. LDS bytes/FLOP is set by wave-grid DUPLICATION (A read by 2 wc-waves,
// B by 2 wr-waves); the 2x2 grid with fat 128-row waves gives 26.7 B/MFLOP
// (QKV, N_REP=6) vs 45.7 at the 128^2 2x2 config -- the session-long
// bottleneck was LDS bandwidth, not schedule. One wave/SIMD (acc 32*N_REP
// VGPR + B frags + in-flight A); overlap is pure ILP: issue B + a0,a1 reads,
// stage tile t+1 (gload_lds, drain distance = full tile), then MFMA(m_i)
// interleaved with read(a_{i+2}); compiler inserts counted lgkmcnt.
// vmcnt(0)+barrier once per tile. No setprio (single wave/SIMD).
template <int MODE, int N_REP>
__global__ __launch_bounds__(256, 1) void gemm_fw(
    const unsigned short* __restrict__ Ab, const unsigned short* __restrict__ Bb,
    int K, int lda, int ldb, long sA, long sB,
    void* __restrict__ o0, void* __restrict__ o1, void* __restrict__ o2) {
  constexpr int BN  = 32 * N_REP;
  constexpr int ASZ = 256 * 64;          // halves per A slot (32 KB)
  constexpr int BSZ = BN * 64;           // halves per B slot
  __shared__ unsigned short lds[2 * ASZ + 2 * BSZ];

  const int tid  = threadIdx.x;
  const int lane = tid & 63;
  const int wv   = tid >> 6;
  const int wr   = wv >> 1, wc = wv & 1;
  const int fr   = lane & 15, fq = lane >> 4;
  int bxi, byi, bzi;
  xcd_swizzle(bxi, byi, bzi);
  const int bm = byi * 256;
  const int bn = bxi * BN;
  const int bz = bzi;

  const unsigned short* A = Ab + (long)bz * sA;
  const unsigned short* B = Bb + (long)bz * sB;

  // staging: thread t -> row tid>>3 per 32-row unit, granule tid&7,
  // source pre-swizzled (gload_lds writes linearly; reads apply same XOR)
  const int row_s = tid >> 3;
  const int col_s = ((tid & 7) ^ (row_s & 7)) * 8;
  const unsigned short* aS = A + (long)(bm + row_s) * lda + col_s;
  const unsigned short* bS = B + (long)(bn + row_s) * ldb + col_s;
  unsigned short* ldsA = lds;
  unsigned short* ldsB = lds + 2 * ASZ;

  // fragment read offsets (bytes); all frag rows have row&7 == fr&7
  const int kg0 = ((0 * 4 + fq) ^ (fr & 7)) * 16;
  const int kg1 = ((1 * 4 + fq) ^ (fr & 7)) * 16;
  const int aRd = (wr * 128 + fr) * 128;            // + mi*2048 + kg
  const int bRd = (wc * 16 * N_REP + fr) * 128;     // + ni*2048 + kg

  f32x4 acc[8][N_REP] = {};
  half8 bf[N_REP][2];
  half8 a0[2], a1[2], a2[2], a3[2], a4[2], a5[2], a6[2], a7[2];

  const int nt = K / 64;

#define STAGE_T(SL, T)                                                             \
  {                                                                                \
    const long kt = (long)(T) * 64;                                                \
    unsigned short* dA = ldsA + (SL) * ASZ + wv * 512;                             \
    unsigned short* dB = ldsB + (SL) * BSZ + wv * 512;                             \
    _Pragma("unroll") for (int i = 0; i < 8; ++i)                                  \
      gload16(aS + (long)(i * 32) * lda + kt, dA + i * 2048);                      \
    _Pragma("unroll") for (int i = 0; i < N_REP; ++i)                              \
      gload16(bS + (long)(i * 32) * ldb + kt, dB + i * 2048);                      \
  }
#define RDA(DST, MI)                                                               \
  DST[0] = *(const half8*)(lA + aRd + (MI) * 2048 + kg0);                          \
  DST[1] = *(const half8*)(lA + aRd + (MI) * 2048 + kg1);
#define MFMAQ(MI, AA)                                                              \
  _Pragma("unroll") for (int ks = 0; ks < 2; ++ks)                                 \
  _Pragma("unroll") for (int ni = 0; ni < N_REP; ++ni)                             \
    acc[MI][ni] = __builtin_amdgcn_mfma_f32_16x16x32_f16(                          \
        AA[ks], bf[ni][ks], acc[MI][ni], 0, 0, 0);

  // ---- prologue: stage tile 0 into slot 0 ----
  STAGE_T(0, 0)
  asm volatile("s_waitcnt vmcnt(0)" ::: "memory");
  __syncthreads();

  for (int tt = 0; tt < nt; ++tt) {
    const int sl = tt & 1;
    const char* lA = (const char*)(ldsA + sl * ASZ);
    const char* lB = (const char*)(ldsB + sl * BSZ);
#pragma unroll
    for (int ni = 0; ni < N_REP; ++ni) {
      bf[ni][0] = *(const half8*)(lB + bRd + ni * 2048 + kg0);
      bf[ni][1] = *(const half8*)(lB + bRd + ni * 2048 + kg1);
    }
    RDA(a0, 0)
    RDA(a1, 1)
    if (tt + 1 < nt) STAGE_T(sl ^ 1, tt + 1)
    MFMAQ(0, a0)
    RDA(a2, 2)
    MFMAQ(1, a1)
    RDA(a3, 3)
    MFMAQ(2, a2)
    RDA(a4, 4)
    MFMAQ(3, a3)
    RDA(a5, 5)
    MFMAQ(4, a4)
    RDA(a6, 6)
    MFMAQ(5, a5)
    RDA(a7, 7)
    MFMAQ(6, a6)
    MFMAQ(7, a7)
    asm volatile("s_waitcnt vmcnt(0)" ::: "memory");
    __syncthreads();
  }
#undef STAGE_T
#undef RDA
#undef MFMAQ

  // epilogue: C/D layout col=lane&15, row=fq*4+reg
  const int row0 = bm + wr * 128 + fq * 4;
  const int col0 = bn + wc * 16 * N_REP + fr;
#pragma unroll
  for (int mi = 0; mi < 8; ++mi) {
#pragma unroll
    for (int ni = 0; ni < N_REP; ++ni) {
      f32x4 c = acc[mi][ni];
      const long r0 = row0 + mi * 16;
      const long e  = col0 + ni * 16;
      if constexpr (MODE == 0) {
        _Float16* q  = (_Float16*)o0;
        _Float16* kk = (_Float16*)o1;
        _Float16* vv = (_Float16*)o2;
#pragma unroll
        for (int j = 0; j < 4; ++j) {
          const long i = r0 + j;
          const float val = c[j];
          if (e < 1024)      q [i * 1024 + e]          = (_Float16)(val * 0.03125f);
          else if (e < 2048) kk[i * 1024 + (e - 1024)] = (_Float16)val;
          else               vv[i * 1024 + (e - 2048)] = (_Float16)val;
        }
      } else if constexpr (MODE == 1) {
        float* C = (float*)o0 + (long)bz * 2048 * 2048;
#pragma unroll
        for (int j = 0; j < 4; ++j) C[(r0 + j) * 2048 + e] = c[j];
      } else {
        float* C = (float*)o0 + (long)bz * 2048 * 1024;
#pragma unroll
        for (int j = 0; j < 4; ++j) C[(r0 + j) * 1024 + e] = c[j];
      }
    }
  }
}

// ---------------- transpose v [b][n][d] -> vT [b][d][n] (fp16) ----------------
__global__ __launch_bounds__(256) void transpose_v(
    const unsigned short* __restrict__ v, unsigned short* __restrict__ vT) {
  __shared__ unsigned short t[64][72];  // +8 pad
  const long b = blockIdx.z;
  const unsigned short* vb = v + b * (2048L * 1024);
  unsigned short* ob = vT + b * (1024L * 2048);
  const int n0 = blockIdx.y * 64;
  const int d0 = blockIdx.x * 64;
  const int tid = threadIdx.x;
  const int r  = tid >> 2;
  const int c0 = (tid & 3) * 16;
  const unsigned short* src = vb + (long)(n0 + r) * 1024 + d0 + c0;
  *(ushort4*)&t[r][c0]      = *(const ushort4*)(src);
  *(ushort4*)&t[r][c0 + 4]  = *(const ushort4*)(src + 4);
  *(ushort4*)&t[r][c0 + 8]  = *(const ushort4*)(src + 8);
  *(ushort4*)&t[r][c0 + 12] = *(const ushort4*)(src + 12);
  __syncthreads();
  union { unsigned short h[8]; ushort8 u; } w0, w1;
#pragma unroll
  for (int j = 0; j < 8; ++j) w0.h[j] = t[c0 + j][r];
#pragma unroll
  for (int j = 0; j < 8; ++j) w1.h[j] = t[c0 + 8 + j][r];
  unsigned short* dst = ob + (long)(d0 + r) * 2048 + n0 + c0;
  *(ushort8*)dst       = w0.u;
  *(ushort8*)(dst + 8) = w1.u;
}

// ---------------- row softmax fp32[2048] -> fp16 in-place ----------------
__global__ __launch_bounds__(256) void softmax_rows(float* __restrict__ S) {
  const long row = blockIdx.x;
  float* p = S + row * 2048;
  const int t = threadIdx.x;
  float4 v0 = *(const float4*)(p + t * 8);
  float4 v1 = *(const float4*)(p + t * 8 + 4);
  float f[8] = {v0.x, v0.y, v0.z, v0.w, v1.x, v1.y, v1.z, v1.w};
  float m = f[0];
#pragma unroll
  for (int j = 1; j < 8; ++j) m = fmaxf(m, f[j]);
  for (int o = 32; o; o >>= 1) m = fmaxf(m, __shfl_xor(m, o));
  __shared__ float redm[4];
  if (!(t & 63)) redm[t >> 6] = m;
  __syncthreads();
  m = fmaxf(fmaxf(redm[0], redm[1]), fmaxf(redm[2], redm[3]));
  float e[8], s = 0.f;
#pragma unroll
  for (int j = 0; j < 8; ++j) { e[j] = __expf(f[j] - m); s += e[j]; }
  for (int o = 32; o; o >>= 1) s += __shfl_xor(s, o);
  __shared__ float reds[4];
  if (!(t & 63)) reds[t >> 6] = s;
  __syncthreads();
  s = reds[0] + reds[1] + reds[2] + reds[3];
  const float inv = 1.0f / s;
  union { _Float16 h[8]; ushort8 u; } r;
#pragma unroll
  for (int j = 0; j < 8; ++j) r.h[j] = (_Float16)(e[j] * inv);
  *(ushort8*)((unsigned short*)p + t * 8) = r.u;  // P fp16, row pitch 4096 halves
}

extern "C" void kernel_launch(void* const* d_in, const int* in_sizes, int n_in,
                              void* d_out, int out_size, void* d_ws, size_t ws_size,
                              hipStream_t stream) {
  const float* x = (const float*)d_in[0];   // [4,2048,1024]
  const float* W = (const float*)d_in[1];   // [3072,1024]
  float* out = (float*)d_out;               // [4,2048,1024] fp32
  char* ws = (char*)d_ws;

  const long MB16 = 16777216;  // 8192*1024*2 bytes
  unsigned short* q  = (unsigned short*)(ws);
  unsigned short* k  = (unsigned short*)(ws + MB16);
  unsigned short* vT = (unsigned short*)(ws + 2 * MB16);
  float*          S  = (float*)(ws + 3 * MB16);              // 64 MiB
  // aliased into S region (dead before S is written):
  unsigned short* xb = (unsigned short*)(ws + 3 * MB16);
  unsigned short* wb = (unsigned short*)(ws + 4 * MB16);
  unsigned short* v  = (unsigned short*)(ws + 4 * MB16 + 6291456);

  // 1. casts
  cast_f32_f16<<<4096, 256, 0, stream>>>(x, xb, 8388608L);
  cast_f32_f16<<<1536, 256, 0, stream>>>(W, wb, 3145728L);
  // 2. qkv = x @ W^T (M=8192, N=3072, K=1024): BM=256 BN=192 -> 16x32 = 512 blocks
  gemm_fw<0, 6><<<dim3(16, 32, 1), 256, 0, stream>>>(
      xb, wb, 1024, 1024, 1024, 0L, 0L, q, k, v);
  // 3. v -> vT per batch
  transpose_v<<<dim3(16, 32, 4), 256, 0, stream>>>(v, vT);
  // 4. S = (q*scale) @ k^T per batch (M=N=2048, K=1024): BM=256 BN=128 -> 512 blocks
  gemm_fw<1, 4><<<dim3(16, 8, 4), 256, 0, stream>>>(
      q, k, 1024, 1024, 1024, 2048L * 1024, 2048L * 1024, S, nullptr, nullptr);
  // 5. row softmax, P fp16 in place (row pitch 4096 halves)
  softmax_rows<<<8192, 256, 0, stream>>>(S);
  // 6. out = P @ vT^T per batch (M=2048, N=1024, K=2048): BM=256 BN=128 -> 256 blocks
  gemm_fw<2, 4><<<dim3(8, 8, 4), 256, 0, stream>>>(
      (unsigned short*)S, vT, 2048, 4096, 2048, 2048L * 4096, 1024L * 2048,
      out, nullptr, nullptr);
}

// Round 13
// 191.421 us; speedup vs baseline: 1.5835x; 1.0063x over previous
//
#include <hip/hip_runtime.h>

using half8   = __attribute__((ext_vector_type(8))) _Float16;
using f32x4   = __attribute__((ext_vector_type(4))) float;
using ushort8 = __attribute__((ext_vector_type(8))) unsigned short;

__device__ __forceinline__ void gload16(const void* g, void* l) {
  __builtin_amdgcn_global_load_lds(
      (const __attribute__((address_space(1))) void*)g,
      (__attribute__((address_space(3))) void*)l, 16, 0, 0);
}

// XCD-aware bijective swizzle with 8x4 2D rects. Requires gx%8==0, gy%4==0.
__device__ __forceinline__ void xcd_swizzle(int& x, int& y, int& z) {
  const int gx = gridDim.x, gy = gridDim.y;
  const int nwg = gx * gy * gridDim.z;
  const int f = blockIdx.x + gx * (blockIdx.y + gy * blockIdx.z);
  const int w = (f & 7) * (nwg >> 3) + (f >> 3);
  const int r = w >> 5, u = w & 31;
  const int nrx = gx >> 3, nry = gy >> 2;
  const int pz  = nrx * nry;
  const int rz  = r / pz, rr = r % pz;
  x = (rr % nrx) * 8 + (u & 7);
  y = (rr / nrx) * 4 + (u >> 3);
  z = rz;
}

// ---------------- cast fp32 -> fp16 ----------------
__global__ __launch_bounds__(256) void cast_f32_f16(
    const float* __restrict__ in, unsigned short* __restrict__ out, long n) {
  long i = ((long)blockIdx.x * 256 + threadIdx.x) * 8;
  if (i >= n) return;
  float4 a = *(const float4*)(in + i);
  float4 b = *(const float4*)(in + i + 4);
  union { _Float16 h[8]; ushort8 u; } r;
  r.h[0] = (_Float16)a.x; r.h[1] = (_Float16)a.y;
  r.h[2] = (_Float16)a.z; r.h[3] = (_Float16)a.w;
  r.h[4] = (_Float16)b.x; r.h[5] = (_Float16)b.y;
  r.h[6] = (_Float16)b.z; r.h[7] = (_Float16)b.w;
  *(ushort8*)(out + i) = r.u;
}

// ======== 4-block/CU NT GEMM: C[M,N] = A[M,K]*B[N,K]^T ========
// BM=BN=128, BK=32, 256 threads (2Mx2N waves), per-wave 64x64 (4x4 of
// 16x16x32 f16). LDS 32KB (2 dbuf slots A+B of 8KB) + <=128 VGPR
// (launch_bounds(256,4)) -> 4 blocks/CU = 4 waves/SIMD, DOUBLE-BUFFERED.
// Session matrix: dbuf at <=2 w/SIMD plateaus at ~70% of achievable LDS BW
// (66us QKV); single-buf at high occupancy = 85us. This is the untested
// quadrant: TLP (4 w/SIMD) hides each block's ds_read latency + drain while
// dbuf hides HBM latency. Rows are 64B (4 granules of 16B); XOR swizzle
// granule ^= row&3, applied on pre-swizzled global source (gload_lds writes
// linearly) and on ds_read addresses. Tile body = R9's proven ILP order.
template <int MODE>
__global__ __launch_bounds__(256, 4) void gemm4b(
    const unsigned short* __restrict__ Ab, const unsigned short* __restrict__ Bb,
    int K, int lda, int ldb, long sA, long sB,
    void* __restrict__ o0, void* __restrict__ o1, void* __restrict__ o2) {
  constexpr int ASZ = 128 * 32;                  // halves per slot (8 KB)
  constexpr int BSZ = 128 * 32;
  __shared__ unsigned short lds[2 * ASZ + 2 * BSZ];  // 32 KB

  const int tid  = threadIdx.x;
  const int lane = tid & 63;
  const int wv   = tid >> 6;
  const int wr   = wv >> 1, wc = wv & 1;
  const int fr   = lane & 15, fq = lane >> 4;
  int bxi, byi, bzi;
  xcd_swizzle(bxi, byi, bzi);
  const int bm = byi * 128;
  const int bn = bxi * 128;
  const int bz = bzi;

  const unsigned short* A = Ab + (long)bz * sA;
  const unsigned short* B = Bb + (long)bz * sB;

  // staging: thread t -> row tid>>2 (0..63) per 64-row issue, granule tid&3,
  // source pre-swizzled: granule (tid&3)^(row&3) (gload_lds writes linearly)
  const int row_s = tid >> 2;
  const int col_s = ((tid & 3) ^ (row_s & 3)) * 8;
  const unsigned short* aS = A + (long)(bm + row_s) * lda + col_s;
  const unsigned short* bS = B + (long)(bn + row_s) * ldb + col_s;
  unsigned short* ldsA = lds;
  unsigned short* ldsB = lds + 2 * ASZ;

  // fragment read offsets (bytes); row = base + fr, base%16==0 -> row&3 == fr&3
  const int kg  = (fq ^ (fr & 3)) * 16;
  const int aRd = (wr * 64 + fr) * 64;   // + mi*1024 + kg
  const int bRd = (wc * 64 + fr) * 64;   // + ni*1024 + kg

  f32x4 acc[4][4] = {};
  half8 bf[4];
  half8 a0, a1, a2, a3;

  const int nt = K / 32;

#define STAGE_T(SL, T)                                                             \
  {                                                                                \
    const long kt = (long)(T) * 32;                                                \
    unsigned short* dA = ldsA + (SL) * ASZ + wv * 512;                             \
    unsigned short* dB = ldsB + (SL) * BSZ + wv * 512;                             \
    gload16(aS + kt, dA);                                                          \
    gload16(aS + (long)64 * lda + kt, dA + 2048);                                  \
    gload16(bS + kt, dB);                                                          \
    gload16(bS + (long)64 * ldb + kt, dB + 2048);                                  \
  }
#define MFMAQ(MI, AA)                                                              \
  _Pragma("unroll") for (int ni = 0; ni < 4; ++ni)                                 \
    acc[MI][ni] = __builtin_amdgcn_mfma_f32_16x16x32_f16(                          \
        AA, bf[ni], acc[MI][ni], 0, 0, 0);

  // ---- prologue: stage tile 0 into slot 0 ----
  STAGE_T(0, 0)
  asm volatile("s_waitcnt vmcnt(0)" ::: "memory");
  __syncthreads();

  for (int tt = 0; tt < nt; ++tt) {
    const int sl = tt & 1;
    const char* lA = (const char*)(ldsA + sl * ASZ);
    const char* lB = (const char*)(ldsB + sl * BSZ);
#pragma unroll
    for (int ni = 0; ni < 4; ++ni)
      bf[ni] = *(const half8*)(lB + bRd + ni * 1024 + kg);
    a0 = *(const half8*)(lA + aRd + 0 * 1024 + kg);
    a1 = *(const half8*)(lA + aRd + 1 * 1024 + kg);
    if (tt + 1 < nt) STAGE_T(sl ^ 1, tt + 1)
    MFMAQ(0, a0)
    a2 = *(const half8*)(lA + aRd + 2 * 1024 + kg);
    MFMAQ(1, a1)
    a3 = *(const half8*)(lA + aRd + 3 * 1024 + kg);
    MFMAQ(2, a2)
    MFMAQ(3, a3)
    asm volatile("s_waitcnt vmcnt(0)" ::: "memory");
    __syncthreads();
  }
#undef STAGE_T
#undef MFMAQ

  // epilogue: C/D layout col=lane&15, row=fq*4+reg
  const int row0 = bm + wr * 64 + fq * 4;
  const int col0 = bn + wc * 64 + fr;
#pragma unroll
  for (int mi = 0; mi < 4; ++mi) {
#pragma unroll
    for (int ni = 0; ni < 4; ++ni) {
      f32x4 c = acc[mi][ni];
      const long r0 = row0 + mi * 16;
      const long e  = col0 + ni * 16;
      if constexpr (MODE == 0) {
        _Float16* q  = (_Float16*)o0;
        _Float16* kk = (_Float16*)o1;
        _Float16* vv = (_Float16*)o2;
#pragma unroll
        for (int j = 0; j < 4; ++j) {
          const long i = r0 + j;
          const float val = c[j];
          if (e < 1024)      q [i * 1024 + e]          = (_Float16)(val * 0.03125f);
          else if (e < 2048) kk[i * 1024 + (e - 1024)] = (_Float16)val;
          else               vv[i * 1024 + (e - 2048)] = (_Float16)val;
        }
      } else if constexpr (MODE == 1) {
        float* C = (float*)o0 + (long)bz * 2048 * 2048;
#pragma unroll
        for (int j = 0; j < 4; ++j) C[(r0 + j) * 2048 + e] = c[j];
      } else {
        float* C = (float*)o0 + (long)bz * 2048 * 1024;
#pragma unroll
        for (int j = 0; j < 4; ++j) C[(r0 + j) * 1024 + e] = c[j];
      }
    }
  }
}

// ---------------- transpose v [b][n][d] -> vT [b][d][n] (fp16) ----------------
__global__ __launch_bounds__(256) void transpose_v(
    const unsigned short* __restrict__ v, unsigned short* __restrict__ vT) {
  __shared__ unsigned short t[64][72];  // +8 pad
  const long b = blockIdx.z;
  const unsigned short* vb = v + b * (2048L * 1024);
  unsigned short* ob = vT + b * (1024L * 2048);
  const int n0 = blockIdx.y * 64;
  const int d0 = blockIdx.x * 64;
  const int tid = threadIdx.x;
  const int r  = tid >> 2;
  const int c0 = (tid & 3) * 16;
  const unsigned short* src = vb + (long)(n0 + r) * 1024 + d0 + c0;
  *(ushort4*)&t[r][c0]      = *(const ushort4*)(src);
  *(ushort4*)&t[r][c0 + 4]  = *(const ushort4*)(src + 4);
  *(ushort4*)&t[r][c0 + 8]  = *(const ushort4*)(src + 8);
  *(ushort4*)&t[r][c0 + 12] = *(const ushort4*)(src + 12);
  __syncthreads();
  union { unsigned short h[8]; ushort8 u; } w0, w1;
#pragma unroll
  for (int j = 0; j < 8; ++j) w0.h[j] = t[c0 + j][r];
#pragma unroll
  for (int j = 0; j < 8; ++j) w1.h[j] = t[c0 + 8 + j][r];
  unsigned short* dst = ob + (long)(d0 + r) * 2048 + n0 + c0;
  *(ushort8*)dst       = w0.u;
  *(ushort8*)(dst + 8) = w1.u;
}

// ---------------- row softmax fp32[2048] -> fp16 in-place ----------------
__global__ __launch_bounds__(256) void softmax_rows(float* __restrict__ S) {
  const long row = blockIdx.x;
  float* p = S + row * 2048;
  const int t = threadIdx.x;
  float4 v0 = *(const float4*)(p + t * 8);
  float4 v1 = *(const float4*)(p + t * 8 + 4);
  float f[8] = {v0.x, v0.y, v0.z, v0.w, v1.x, v1.y, v1.z, v1.w};
  float m = f[0];
#pragma unroll
  for (int j = 1; j < 8; ++j) m = fmaxf(m, f[j]);
  for (int o = 32; o; o >>= 1) m = fmaxf(m, __shfl_xor(m, o));
  __shared__ float redm[4];
  if (!(t & 63)) redm[t >> 6] = m;
  __syncthreads();
  m = fmaxf(fmaxf(redm[0], redm[1]), fmaxf(redm[2], redm[3]));
  float e[8], s = 0.f;
#pragma unroll
  for (int j = 0; j < 8; ++j) { e[j] = __expf(f[j] - m); s += e[j]; }
  for (int o = 32; o; o >>= 1) s += __shfl_xor(s, o);
  __shared__ float reds[4];
  if (!(t & 63)) reds[t >> 6] = s;
  __syncthreads();
  s = reds[0] + reds[1] + reds[2] + reds[3];
  const float inv = 1.0f / s;
  union { _Float16 h[8]; ushort8 u; } r;
#pragma unroll
  for (int j = 0; j < 8; ++j) r.h[j] = (_Float16)(e[j] * inv);
  *(ushort8*)((unsigned short*)p + t * 8) = r.u;  // P fp16, row pitch 4096 halves
}

extern "C" void kernel_launch(void* const* d_in, const int* in_sizes, int n_in,
                              void* d_out, int out_size, void* d_ws, size_t ws_size,
                              hipStream_t stream) {
  const float* x = (const float*)d_in[0];   // [4,2048,1024]
  const float* W = (const float*)d_in[1];   // [3072,1024]
  float* out = (float*)d_out;               // [4,2048,1024] fp32
  char* ws = (char*)d_ws;

  const long MB16 = 16777216;  // 8192*1024*2 bytes
  unsigned short* q  = (unsigned short*)(ws);
  unsigned short* k  = (unsigned short*)(ws + MB16);
  unsigned short* vT = (unsigned short*)(ws + 2 * MB16);
  float*          S  = (float*)(ws + 3 * MB16);              // 64 MiB
  // aliased into S region (dead before S is written):
  unsigned short* xb = (unsigned short*)(ws + 3 * MB16);
  unsigned short* wb = (unsigned short*)(ws + 4 * MB16);
  unsigned short* v  = (unsigned short*)(ws + 4 * MB16 + 6291456);

  // 1. casts
  cast_f32_f16<<<4096, 256, 0, stream>>>(x, xb, 8388608L);
  cast_f32_f16<<<1536, 256, 0, stream>>>(W, wb, 3145728L);
  // 2. qkv = x @ W^T (M=8192, N=3072, K=1024): 24x64 = 1536 blocks
  gemm4b<0><<<dim3(24, 64, 1), 256, 0, stream>>>(
      xb, wb, 1024, 1024, 1024, 0L, 0L, q, k, v);
  // 3. v -> vT per batch
  transpose_v<<<dim3(16, 32, 4), 256, 0, stream>>>(v, vT);
  // 4. S = (q*scale) @ k^T per batch (M=N=2048, K=1024): 16x16x4 = 1024 blocks
  gemm4b<1><<<dim3(16, 16, 4), 256, 0, stream>>>(
      q, k, 1024, 1024, 1024, 2048L * 1024, 2048L * 1024, S, nullptr, nullptr);
  // 5. row softmax, P fp16 in place (row pitch 4096 halves)
  softmax_rows<<<8192, 256, 0, stream>>>(S);
  // 6. out = P @ vT^T per batch (M=2048, N=1024, K=2048): 8x16x4 = 512 blocks
  gemm4b<2><<<dim3(8, 16, 4), 256, 0, stream>>>(
      (unsigned short*)S, vT, 2048, 4096, 2048, 2048L * 4096, 1024L * 2048,
      out, nullptr, nullptr);
}

// Round 14
// 190.146 us; speedup vs baseline: 1.5941x; 1.0067x over previous
//
#include <hip/hip_runtime.h>

using half8   = __attribute__((ext_vector_type(8))) _Float16;
using f32x4   = __attribute__((ext_vector_type(4))) float;
using ushort8 = __attribute__((ext_vector_type(8))) unsigned short;

__device__ __forceinline__ void gload16(const void* g, void* l) {
  __builtin_amdgcn_global_load_lds(
      (const __attribute__((address_space(1))) void*)g,
      (__attribute__((address_space(3))) void*)l, 16, 0, 0);
}

// XCD-aware bijective swizzle with 8x4 2D rects. Requires gx%8==0, gy%4==0.
__device__ __forceinline__ void xcd_swizzle(int& x, int& y, int& z) {
  const int gx = gridDim.x, gy = gridDim.y;
  const int nwg = gx * gy * gridDim.z;
  const int f = blockIdx.x + gx * (blockIdx.y + gy * blockIdx.z);
  const int w = (f & 7) * (nwg >> 3) + (f >> 3);
  const int r = w >> 5, u = w & 31;
  const int nrx = gx >> 3, nry = gy >> 2;
  const int pz  = nrx * nry;
  const int rz  = r / pz, rr = r % pz;
  x = (rr % nrx) * 8 + (u & 7);
  y = (rr / nrx) * 4 + (u >> 3);
  z = rz;
}

// ---------------- cast fp32 -> fp16 ----------------
__global__ __launch_bounds__(256) void cast_f32_f16(
    const float* __restrict__ in, unsigned short* __restrict__ out, long n) {
  long i = ((long)blockIdx.x * 256 + threadIdx.x) * 8;
  if (i >= n) return;
  float4 a = *(const float4*)(in + i);
  float4 b = *(const float4*)(in + i + 4);
  union { _Float16 h[8]; ushort8 u; } r;
  r.h[0] = (_Float16)a.x; r.h[1] = (_Float16)a.y;
  r.h[2] = (_Float16)a.z; r.h[3] = (_Float16)a.w;
  r.h[4] = (_Float16)b.x; r.h[5] = (_Float16)b.y;
  r.h[6] = (_Float16)b.z; r.h[7] = (_Float16)b.w;
  *(ushort8*)(out + i) = r.u;
}

// ======== 4-block/CU NT GEMM: C[M,N] = A[M,K]*B[N,K]^T ========
// BM=BN=128, BK=32, 256 threads (2Mx2N waves), per-wave 64x64 (4x4 of
// 16x16x32 f16). LDS 32KB (2 dbuf slots A+B of 8KB), <=128 unified regs
// -> 4 blocks/CU = 4 waves/SIMD, double-buffered (TLP hides ds_read latency
// and the per-tile drain; dbuf hides HBM latency).
// SWIZZLE FIX vs R13: stored granule = logical ^ ((row>>1)&3) (was row&3).
// Quarter-wave bank model: a b128 read services 16 lanes/group; conflict-free
// needs 8 distinct 16B bank-slots per group. Rows stride 64B (parity flips
// bank half) -> XOR on row>>1 makes even/odd fr classes each sweep all 4
// granules: bank_start = (fr&1)*16 + (fq^((fr>>1)&3))*4 covers all 8 slots
// twice -> 2 lanes/bank = free (m136). R13's row&3 gave 4 lanes/slot = 4-way
// (6.29M conflicts measured).
template <int MODE>
__global__ __launch_bounds__(256, 4) void gemm4b(
    const unsigned short* __restrict__ Ab, const unsigned short* __restrict__ Bb,
    int K, int lda, int ldb, long sA, long sB,
    void* __restrict__ o0, void* __restrict__ o1, void* __restrict__ o2) {
  constexpr int ASZ = 128 * 32;                  // halves per slot (8 KB)
  constexpr int BSZ = 128 * 32;
  __shared__ unsigned short lds[2 * ASZ + 2 * BSZ];  // 32 KB

  const int tid  = threadIdx.x;
  const int lane = tid & 63;
  const int wv   = tid >> 6;
  const int wr   = wv >> 1, wc = wv & 1;
  const int fr   = lane & 15, fq = lane >> 4;
  int bxi, byi, bzi;
  xcd_swizzle(bxi, byi, bzi);
  const int bm = byi * 128;
  const int bn = bxi * 128;
  const int bz = bzi;

  const unsigned short* A = Ab + (long)bz * sA;
  const unsigned short* B = Bb + (long)bz * sB;

  // staging: thread t -> row tid>>2 (0..63) per 64-row issue, granule tid&3,
  // source pre-swizzled: granule (tid&3)^((row>>1)&3) (gload_lds writes linearly)
  const int row_s = tid >> 2;
  const int col_s = ((tid & 3) ^ ((row_s >> 1) & 3)) * 8;
  const unsigned short* aS = A + (long)(bm + row_s) * lda + col_s;
  const unsigned short* bS = B + (long)(bn + row_s) * ldb + col_s;
  unsigned short* ldsA = lds;
  unsigned short* ldsB = lds + 2 * ASZ;

  // fragment read offsets (bytes); frag row = base + fr with base%16==0
  // -> ((base+fr)>>1)&3 == (fr>>1)&3
  const int kg  = (fq ^ ((fr >> 1) & 3)) * 16;
  const int aRd = (wr * 64 + fr) * 64;   // + mi*1024 + kg
  const int bRd = (wc * 64 + fr) * 64;   // + ni*1024 + kg

  f32x4 acc[4][4] = {};
  half8 bf[4];
  half8 a0, a1, a2, a3;

  const int nt = K / 32;

#define STAGE_T(SL, T)                                                             \
  {                                                                                \
    const long kt = (long)(T) * 32;                                                \
    unsigned short* dA = ldsA + (SL) * ASZ + wv * 512;                             \
    unsigned short* dB = ldsB + (SL) * BSZ + wv * 512;                             \
    gload16(aS + kt, dA);                                                          \
    gload16(aS + (long)64 * lda + kt, dA + 2048);                                  \
    gload16(bS + kt, dB);                                                          \
    gload16(bS + (long)64 * ldb + kt, dB + 2048);                                  \
  }
#define MFMAQ(MI, AA)                                                              \
  _Pragma("unroll") for (int ni = 0; ni < 4; ++ni)                                 \
    acc[MI][ni] = __builtin_amdgcn_mfma_f32_16x16x32_f16(                          \
        AA, bf[ni], acc[MI][ni], 0, 0, 0);

  // ---- prologue: stage tile 0 into slot 0 ----
  STAGE_T(0, 0)
  asm volatile("s_waitcnt vmcnt(0)" ::: "memory");
  __syncthreads();

  for (int tt = 0; tt < nt; ++tt) {
    const int sl = tt & 1;
    const char* lA = (const char*)(ldsA + sl * ASZ);
    const char* lB = (const char*)(ldsB + sl * BSZ);
#pragma unroll
    for (int ni = 0; ni < 4; ++ni)
      bf[ni] = *(const half8*)(lB + bRd + ni * 1024 + kg);
    a0 = *(const half8*)(lA + aRd + 0 * 1024 + kg);
    a1 = *(const half8*)(lA + aRd + 1 * 1024 + kg);
    if (tt + 1 < nt) STAGE_T(sl ^ 1, tt + 1)
    MFMAQ(0, a0)
    a2 = *(const half8*)(lA + aRd + 2 * 1024 + kg);
    MFMAQ(1, a1)
    a3 = *(const half8*)(lA + aRd + 3 * 1024 + kg);
    MFMAQ(2, a2)
    MFMAQ(3, a3)
    asm volatile("s_waitcnt vmcnt(0)" ::: "memory");
    __syncthreads();
  }
#undef STAGE_T
#undef MFMAQ

  // epilogue: C/D layout col=lane&15, row=fq*4+reg
  const int row0 = bm + wr * 64 + fq * 4;
  const int col0 = bn + wc * 64 + fr;
#pragma unroll
  for (int mi = 0; mi < 4; ++mi) {
#pragma unroll
    for (int ni = 0; ni < 4; ++ni) {
      f32x4 c = acc[mi][ni];
      const long r0 = row0 + mi * 16;
      const long e  = col0 + ni * 16;
      if constexpr (MODE == 0) {
        _Float16* q  = (_Float16*)o0;
        _Float16* kk = (_Float16*)o1;
        _Float16* vv = (_Float16*)o2;
#pragma unroll
        for (int j = 0; j < 4; ++j) {
          const long i = r0 + j;
          const float val = c[j];
          if (e < 1024)      q [i * 1024 + e]          = (_Float16)(val * 0.03125f);
          else if (e < 2048) kk[i * 1024 + (e - 1024)] = (_Float16)val;
          else               vv[i * 1024 + (e - 2048)] = (_Float16)val;
        }
      } else if constexpr (MODE == 1) {
        float* C = (float*)o0 + (long)bz * 2048 * 2048;
#pragma unroll
        for (int j = 0; j < 4; ++j) C[(r0 + j) * 2048 + e] = c[j];
      } else {
        float* C = (float*)o0 + (long)bz * 2048 * 1024;
#pragma unroll
        for (int j = 0; j < 4; ++j) C[(r0 + j) * 1024 + e] = c[j];
      }
    }
  }
}

// ---------------- transpose v [b][n][d] -> vT [b][d][n] (fp16) ----------------
__global__ __launch_bounds__(256) void transpose_v(
    const unsigned short* __restrict__ v, unsigned short* __restrict__ vT) {
  __shared__ unsigned short t[64][72];  // +8 pad
  const long b = blockIdx.z;
  const unsigned short* vb = v + b * (2048L * 1024);
  unsigned short* ob = vT + b * (1024L * 2048);
  const int n0 = blockIdx.y * 64;
  const int d0 = blockIdx.x * 64;
  const int tid = threadIdx.x;
  const int r  = tid >> 2;
  const int c0 = (tid & 3) * 16;
  const unsigned short* src = vb + (long)(n0 + r) * 1024 + d0 + c0;
  *(ushort4*)&t[r][c0]      = *(const ushort4*)(src);
  *(ushort4*)&t[r][c0 + 4]  = *(const ushort4*)(src + 4);
  *(ushort4*)&t[r][c0 + 8]  = *(const ushort4*)(src + 8);
  *(ushort4*)&t[r][c0 + 12] = *(const ushort4*)(src + 12);
  __syncthreads();
  union { unsigned short h[8]; ushort8 u; } w0, w1;
#pragma unroll
  for (int j = 0; j < 8; ++j) w0.h[j] = t[c0 + j][r];
#pragma unroll
  for (int j = 0; j < 8; ++j) w1.h[j] = t[c0 + 8 + j][r];
  unsigned short* dst = ob + (long)(d0 + r) * 2048 + n0 + c0;
  *(ushort8*)dst       = w0.u;
  *(ushort8*)(dst + 8) = w1.u;
}

// ---------------- row softmax fp32[2048] -> fp16 in-place ----------------
__global__ __launch_bounds__(256) void softmax_rows(float* __restrict__ S) {
  const long row = blockIdx.x;
  float* p = S + row * 2048;
  const int t = threadIdx.x;
  float4 v0 = *(const float4*)(p + t * 8);
  float4 v1 = *(const float4*)(p + t * 8 + 4);
  float f[8] = {v0.x, v0.y, v0.z, v0.w, v1.x, v1.y, v1.z, v1.w};
  float m = f[0];
#pragma unroll
  for (int j = 1; j < 8; ++j) m = fmaxf(m, f[j]);
  for (int o = 32; o; o >>= 1) m = fmaxf(m, __shfl_xor(m, o));
  __shared__ float redm[4];
  if (!(t & 63)) redm[t >> 6] = m;
  __syncthreads();
  m = fmaxf(fmaxf(redm[0], redm[1]), fmaxf(redm[2], redm[3]));
  float e[8], s = 0.f;
#pragma unroll
  for (int j = 0; j < 8; ++j) { e[j] = __expf(f[j] - m); s += e[j]; }
  for (int o = 32; o; o >>= 1) s += __shfl_xor(s, o);
  __shared__ float reds[4];
  if (!(t & 63)) reds[t >> 6] = s;
  __syncthreads();
  s = reds[0] + reds[1] + reds[2] + reds[3];
  const float inv = 1.0f / s;
  union { _Float16 h[8]; ushort8 u; } r;
#pragma unroll
  for (int j = 0; j < 8; ++j) r.h[j] = (_Float16)(e[j] * inv);
  *(ushort8*)((unsigned short*)p + t * 8) = r.u;  // P fp16, row pitch 4096 halves
}

extern "C" void kernel_launch(void* const* d_in, const int* in_sizes, int n_in,
                              void* d_out, int out_size, void* d_ws, size_t ws_size,
                              hipStream_t stream) {
  const float* x = (const float*)d_in[0];   // [4,2048,1024]
  const float* W = (const float*)d_in[1];   // [3072,1024]
  float* out = (float*)d_out;               // [4,2048,1024] fp32
  char* ws = (char*)d_ws;

  const long MB16 = 16777216;  // 8192*1024*2 bytes
  unsigned short* q  = (unsigned short*)(ws);
  unsigned short* k  = (unsigned short*)(ws + MB16);
  unsigned short* vT = (unsigned short*)(ws + 2 * MB16);
  float*          S  = (float*)(ws + 3 * MB16);              // 64 MiB
  // aliased into S region (dead before S is written):
  unsigned short* xb = (unsigned short*)(ws + 3 * MB16);
  unsigned short* wb = (unsigned short*)(ws + 4 * MB16);
  unsigned short* v  = (unsigned short*)(ws + 4 * MB16 + 6291456);

  // 1. casts
  cast_f32_f16<<<4096, 256, 0, stream>>>(x, xb, 8388608L);
  cast_f32_f16<<<1536, 256, 0, stream>>>(W, wb, 3145728L);
  // 2. qkv = x @ W^T (M=8192, N=3072, K=1024): 24x64 = 1536 blocks
  gemm4b<0><<<dim3(24, 64, 1), 256, 0, stream>>>(
      xb, wb, 1024, 1024, 1024, 0L, 0L, q, k, v);
  // 3. v -> vT per batch
  transpose_v<<<dim3(16, 32, 4), 256, 0, stream>>>(v, vT);
  // 4. S = (q*scale) @ k^T per batch (M=N=2048, K=1024): 16x16x4 = 1024 blocks
  gemm4b<1><<<dim3(16, 16, 4), 256, 0, stream>>>(
      q, k, 1024, 1024, 1024, 2048L * 1024, 2048L * 1024, S, nullptr, nullptr);
  // 5. row softmax, P fp16 in place (row pitch 4096 halves)
  softmax_rows<<<8192, 256, 0, stream>>>(S);
  // 6. out = P @ vT^T per batch (M=2048, N=1024, K=2048): 8x16x4 = 512 blocks
  gemm4b<2><<<dim3(8, 16, 4), 256, 0, stream>>>(
      (unsigned short*)S, vT, 2048, 4096, 2048, 2048L * 4096, 1024L * 2048,
      out, nullptr, nullptr);
}